// Round 8
// baseline (747.112 us; speedup 1.0000x reference)
//
#include <hip/hip_runtime.h>
#include <hip/hip_fp16.h>
#include <math.h>

#define N_NODES 100000
#define N_EDGES 1600000
#define F_DIM 64
#define BSH 7                              // 128 nodes per bucket
#define BNODES 128
#define NBUCK ((N_NODES + BNODES - 1) / BNODES)   // 782
#define CAP 4096                           // slots/bucket (mean 2048, ~45 sigma headroom)
#define EPT 16
#define TILE (256 * EPT)                   // 4096 edges per pass1 block

// ---------------- init bucket cursors ----------------
__global__ __launch_bounds__(256) void init_k(int* __restrict__ bcur) {
    int i = blockIdx.x * 256 + threadIdx.x;
    if (i < NBUCK) bcur[i] = i * CAP;
}

// ---------------- pass1: single-pass bucket scatter (fixed-capacity) ----------------
__global__ __launch_bounds__(256) void pass1_k(const int* __restrict__ src,
                                               const int* __restrict__ dst,
                                               int* __restrict__ bcur,
                                               unsigned int* __restrict__ tmp, int E) {
    __shared__ int lcnt[NBUCK];
    __shared__ int lbase[NBUCK];
    for (int i = threadIdx.x; i < NBUCK; i += 256) lcnt[i] = 0;
    __syncthreads();

    int4 sreg[EPT / 4], dreg[EPT / 4];
    int base4 = blockIdx.x * (TILE / 4);
#pragma unroll
    for (int j = 0; j < EPT / 4; ++j) {
        int i4 = base4 + j * 256 + threadIdx.x;
        if (i4 < E / 4) {
            sreg[j] = ((const int4*)src)[i4];
            dreg[j] = ((const int4*)dst)[i4];
            atomicAdd(&lcnt[dreg[j].x >> BSH], 1);
            atomicAdd(&lcnt[dreg[j].y >> BSH], 1);
            atomicAdd(&lcnt[dreg[j].z >> BSH], 1);
            atomicAdd(&lcnt[dreg[j].w >> BSH], 1);
        } else {
            dreg[j].x = -1;
        }
    }
    __syncthreads();
    for (int b = threadIdx.x; b < NBUCK; b += 256) {
        int c = lcnt[b];
        lbase[b] = c ? atomicAdd(&bcur[b], c) : 0;
        lcnt[b] = 0;
    }
    __syncthreads();
#pragma unroll
    for (int j = 0; j < EPT / 4; ++j) {
        if (dreg[j].x >= 0) {
            int d, s, b, r;
            d = dreg[j].x; s = sreg[j].x; b = d >> BSH;
            r = atomicAdd(&lcnt[b], 1);
            tmp[lbase[b] + r] = (unsigned int)s | ((unsigned int)(d & (BNODES - 1)) << 17);
            d = dreg[j].y; s = sreg[j].y; b = d >> BSH;
            r = atomicAdd(&lcnt[b], 1);
            tmp[lbase[b] + r] = (unsigned int)s | ((unsigned int)(d & (BNODES - 1)) << 17);
            d = dreg[j].z; s = sreg[j].z; b = d >> BSH;
            r = atomicAdd(&lcnt[b], 1);
            tmp[lbase[b] + r] = (unsigned int)s | ((unsigned int)(d & (BNODES - 1)) << 17);
            d = dreg[j].w; s = sreg[j].w; b = d >> BSH;
            r = atomicAdd(&lcnt[b], 1);
            tmp[lbase[b] + r] = (unsigned int)s | ((unsigned int)(d & (BNODES - 1)) << 17);
        }
    }
}

// ---------------- deginv: per-bucket degree count -> inv sqrt ----------------
__global__ __launch_bounds__(256) void deginv_k(const unsigned int* __restrict__ tmp,
                                                const int* __restrict__ bcur,
                                                float* __restrict__ inv) {
    __shared__ int cnt[BNODES];
    int b = blockIdx.x;
    int beg0 = b * CAP;
    int cntb = bcur[b] - beg0;
    if (threadIdx.x < BNODES) cnt[threadIdx.x] = 0;
    __syncthreads();
    for (int i = threadIdx.x; i < cntb; i += 256)
        atomicAdd(&cnt[tmp[beg0 + i] >> 17], 1);
    __syncthreads();
    int n = (b << BSH) + threadIdx.x;
    if (threadIdx.x < BNODES && n < N_NODES)
        inv[n] = rsqrtf((float)(cnt[threadIdx.x] + 1));
}

// ---------------- linear: h_pre = (x*W + b) * inv[n], fp16 [N][64] ----------------
__global__ __launch_bounds__(256) void linear_k(const float* __restrict__ x,
                                                const float* __restrict__ W,
                                                const float* __restrict__ bias,
                                                const float* __restrict__ inv,
                                                __half* __restrict__ h, int N) {
    __shared__ float Ws[F_DIM][F_DIM];
    __shared__ float bs[F_DIM];
    for (int i = threadIdx.x; i < F_DIM * F_DIM; i += 256) Ws[i >> 6][i & 63] = W[i];
    if (threadIdx.x < F_DIM) bs[threadIdx.x] = bias[threadIdx.x];
    __syncthreads();

    int n = blockIdx.x * 256 + threadIdx.x;
    if (n >= N) return;

    float xr[F_DIM];
    const float4* xp = (const float4*)(x + (size_t)n * F_DIM);
#pragma unroll
    for (int k4 = 0; k4 < 16; ++k4) {
        float4 v = xp[k4];
        xr[k4 * 4 + 0] = v.x; xr[k4 * 4 + 1] = v.y;
        xr[k4 * 4 + 2] = v.z; xr[k4 * 4 + 3] = v.w;
    }
    float invn = inv[n];
    __half* hp = h + (size_t)n * F_DIM;
#pragma unroll 1
    for (int f0 = 0; f0 < F_DIM; f0 += 4) {
        float a0 = bs[f0 + 0], a1 = bs[f0 + 1], a2 = bs[f0 + 2], a3 = bs[f0 + 3];
#pragma unroll
        for (int k = 0; k < F_DIM; ++k) {
            float xv = xr[k];
            a0 += xv * Ws[k][f0 + 0];
            a1 += xv * Ws[k][f0 + 1];
            a2 += xv * Ws[k][f0 + 2];
            a3 += xv * Ws[k][f0 + 3];
        }
        union { __half2 h2[2]; float2 f2; } u;
        u.h2[0] = __floats2half2_rn(a0 * invn, a1 * invn);
        u.h2[1] = __floats2half2_rn(a2 * invn, a3 * invn);
        *((float2*)(hp + f0)) = u.f2;
    }
}

// ---------------- gelu (tanh approximation, jax.nn.gelu default) ----------------
__device__ __forceinline__ float gelu1(float x) {
    float x3 = x * x * x;
    float t = tanhf(0.7978845608028654f * (x + 0.044715f * x3));
    return 0.5f * x * (1.0f + t);
}

// ---------------- gather2: block per bucket; LDS fp32 out-tile; unsorted edges ----------------
__global__ __launch_bounds__(256) void gather2_k(const __half* __restrict__ h,   // h_pre [N][64]
                                                 const float* __restrict__ inv,
                                                 const int* __restrict__ bcur,
                                                 const unsigned int* __restrict__ tmp,
                                                 float* __restrict__ out) {
    __shared__ float tile[BNODES][F_DIM];   // 32 KB
    int b = blockIdx.x;
    int beg0 = b * CAP;
    int ecnt = bcur[b] - beg0;
    int tid = threadIdx.x;

    float4 z = {0.f, 0.f, 0.f, 0.f};
    for (int i = tid; i < BNODES * F_DIM / 4; i += 256) ((float4*)&tile[0][0])[i] = z;
    __syncthreads();

    int hw = tid >> 5;          // 8 half-waves per block
    int fl = tid & 31;          // feature pair
    const unsigned int* tb = tmp + beg0;

    int e = hw;
    for (; e + 56 < ecnt; e += 64) {
        unsigned int w[8];
        __half2 v[8];
#pragma unroll
        for (int u = 0; u < 8; ++u) w[u] = tb[e + 8 * u];
#pragma unroll
        for (int u = 0; u < 8; ++u)
            v[u] = *((const __half2*)(h + (size_t)(w[u] & 0x1FFFFu) * F_DIM) + fl);
#pragma unroll
        for (int u = 0; u < 8; ++u) {
            float2 f = __half22float2(v[u]);
            int ld = (int)(w[u] >> 17);
            atomicAdd(&tile[ld][2 * fl], f.x);
            atomicAdd(&tile[ld][2 * fl + 1], f.y);
        }
    }
    for (; e < ecnt; e += 8) {
        unsigned int w = tb[e];
        __half2 v = *((const __half2*)(h + (size_t)(w & 0x1FFFFu) * F_DIM) + fl);
        float2 f = __half22float2(v);
        int ld = (int)(w >> 17);
        atomicAdd(&tile[ld][2 * fl], f.x);
        atomicAdd(&tile[ld][2 * fl + 1], f.y);
    }
    __syncthreads();

    int node0 = b << BSH;
    for (int i = tid; i < BNODES * F_DIM; i += 256) {
        int ln = i >> 6;
        int f = i & 63;
        int n = node0 + ln;
        if (n < N_NODES) {
            float invn = inv[n];
            float hv = __half2float(h[(size_t)n * F_DIM + f]);   // h_pre[n] = h[n]*invn
            out[(size_t)n * F_DIM + f] = gelu1((tile[ln][f] + hv) * invn);
        }
    }
}

extern "C" void kernel_launch(void* const* d_in, const int* in_sizes, int n_in,
                              void* d_out, int out_size, void* d_ws, size_t ws_size,
                              hipStream_t stream) {
    const float* x    = (const float*)d_in[0];
    const int*   ei   = (const int*)d_in[1];
    const float* W    = (const float*)d_in[2];
    const float* bias = (const float*)d_in[3];
    float* out = (float*)d_out;

    const int* src = ei;             // edge_index[0]
    const int* dst = ei + N_EDGES;   // edge_index[1]

    // workspace (~26 MB)
    unsigned int* tmp  = (unsigned int*)d_ws;             // NBUCK*CAP uints = 12.8 MB
    float*        inv  = (float*)(tmp + (size_t)NBUCK * CAP);  // N floats
    int*          bcur = (int*)(inv + N_NODES);           // NBUCK ints
    size_t off = (size_t)(bcur + NBUCK) - (size_t)d_ws;
    off = (off + 31) & ~(size_t)31;
    __half* h = (__half*)((char*)d_ws + off);             // N*64 halves = 12.8 MB

    init_k<<<(NBUCK + 255) / 256, 256, 0, stream>>>(bcur);
    pass1_k<<<(N_EDGES + TILE - 1) / TILE, 256, 0, stream>>>(src, dst, bcur, tmp, N_EDGES);
    deginv_k<<<NBUCK, 256, 0, stream>>>(tmp, bcur, inv);
    linear_k<<<(N_NODES + 255) / 256, 256, 0, stream>>>(x, W, bias, inv, h, N_NODES);
    gather2_k<<<NBUCK, 256, 0, stream>>>(h, inv, bcur, tmp, out);
}

// Round 9
// 125.044 us; speedup vs baseline: 5.9748x; 5.9748x over previous
//
#include <hip/hip_runtime.h>
#include <hip/hip_fp16.h>
#include <math.h>

#define N_NODES 100000
#define N_EDGES 1600000
#define F_DIM 64
#define BSH 9                              // 512 nodes per bucket
#define BNODES 512
#define NBUCK ((N_NODES + BNODES - 1) / BNODES)   // 196
#define CAP 16384                          // slots/bucket (mean 8192, ~90 sigma headroom)
#define EPT 32
#define TILE (256 * EPT)                   // 8192 edges per pass1 block

// ---------------- init bucket cursors ----------------
__global__ __launch_bounds__(256) void init_k(int* __restrict__ bcur) {
    int i = blockIdx.x * 256 + threadIdx.x;
    if (i < NBUCK) bcur[i] = i * CAP;
}

// ---------------- pass1: single-pass bucket scatter (fixed-capacity) ----------------
__global__ __launch_bounds__(256) void pass1_k(const int* __restrict__ src,
                                               const int* __restrict__ dst,
                                               int* __restrict__ bcur,
                                               unsigned int* __restrict__ tmp, int E) {
    __shared__ int lcnt[NBUCK];
    __shared__ int lbase[NBUCK];
    for (int i = threadIdx.x; i < NBUCK; i += 256) lcnt[i] = 0;
    __syncthreads();

    int4 sreg[EPT / 4], dreg[EPT / 4];
    int base4 = blockIdx.x * (TILE / 4);
#pragma unroll
    for (int j = 0; j < EPT / 4; ++j) {
        int i4 = base4 + j * 256 + threadIdx.x;
        if (i4 < E / 4) {
            sreg[j] = ((const int4*)src)[i4];
            dreg[j] = ((const int4*)dst)[i4];
            atomicAdd(&lcnt[dreg[j].x >> BSH], 1);
            atomicAdd(&lcnt[dreg[j].y >> BSH], 1);
            atomicAdd(&lcnt[dreg[j].z >> BSH], 1);
            atomicAdd(&lcnt[dreg[j].w >> BSH], 1);
        } else {
            dreg[j].x = -1;
        }
    }
    __syncthreads();
    for (int b = threadIdx.x; b < NBUCK; b += 256) {
        int c = lcnt[b];
        lbase[b] = c ? atomicAdd(&bcur[b], c) : 0;
        lcnt[b] = 0;
    }
    __syncthreads();
#pragma unroll
    for (int j = 0; j < EPT / 4; ++j) {
        if (dreg[j].x >= 0) {
            int d, s, b, r;
            d = dreg[j].x; s = sreg[j].x; b = d >> BSH;
            r = atomicAdd(&lcnt[b], 1);
            tmp[lbase[b] + r] = (unsigned int)s | ((unsigned int)(d & (BNODES - 1)) << 17);
            d = dreg[j].y; s = sreg[j].y; b = d >> BSH;
            r = atomicAdd(&lcnt[b], 1);
            tmp[lbase[b] + r] = (unsigned int)s | ((unsigned int)(d & (BNODES - 1)) << 17);
            d = dreg[j].z; s = sreg[j].z; b = d >> BSH;
            r = atomicAdd(&lcnt[b], 1);
            tmp[lbase[b] + r] = (unsigned int)s | ((unsigned int)(d & (BNODES - 1)) << 17);
            d = dreg[j].w; s = sreg[j].w; b = d >> BSH;
            r = atomicAdd(&lcnt[b], 1);
            tmp[lbase[b] + r] = (unsigned int)s | ((unsigned int)(d & (BNODES - 1)) << 17);
        }
    }
}

// ---------------- passB: per-bucket node sort (in-place), rowinfo, inv ----------------
__global__ __launch_bounds__(256) void passB_k(unsigned int* __restrict__ tmp,  // in: bucketed; out: esrc (in place)
                                               const int* __restrict__ bcur,
                                               unsigned int* __restrict__ rowinfo,
                                               float* __restrict__ inv) {
    __shared__ unsigned int buf[CAP];   // 64 KB
    __shared__ int cnt[BNODES];
    __shared__ int cur[BNODES];
    __shared__ int ls[256];
    int b = blockIdx.x;
    int beg0 = b * CAP;
    int cntb = bcur[b] - beg0;

    cnt[threadIdx.x] = 0;
    cnt[threadIdx.x + 256] = 0;
    __syncthreads();
    for (int i = threadIdx.x; i < cntb; i += 256) {
        unsigned int v = tmp[beg0 + i];
        buf[i] = v;
        atomicAdd(&cnt[v >> 17], 1);
    }
    __syncthreads();

    int a0 = cnt[2 * threadIdx.x];
    int a1 = cnt[2 * threadIdx.x + 1];
    int tsum = a0 + a1;
    ls[threadIdx.x] = tsum;
    __syncthreads();
    for (int off = 1; off < 256; off <<= 1) {
        int p = (threadIdx.x >= off) ? ls[threadIdx.x - off] : 0;
        __syncthreads();
        ls[threadIdx.x] += p;
        __syncthreads();
    }
    int excl = ls[threadIdx.x] - tsum;
    int p0 = beg0 + excl;
    int p1 = p0 + a0;
    cur[2 * threadIdx.x] = p0;
    cur[2 * threadIdx.x + 1] = p1;
    int n0 = (b << BSH) + 2 * threadIdx.x;
    if (n0 < N_NODES) {
        rowinfo[n0] = (unsigned int)p0 | ((unsigned int)a0 << 22);
        inv[n0] = rsqrtf((float)(a0 + 1));
    }
    if (n0 + 1 < N_NODES) {
        rowinfo[n0 + 1] = (unsigned int)p1 | ((unsigned int)a1 << 22);
        inv[n0 + 1] = rsqrtf((float)(a1 + 1));
    }
    __syncthreads();

    for (int i = threadIdx.x; i < cntb; i += 256) {
        unsigned int v = buf[i];
        int pos = atomicAdd(&cur[v >> 17], 1);
        tmp[pos] = v & 0x1FFFFu;
    }
}

// ---------------- linear: h_pre = (x*W + b) * inv[n], fp16 [N][64] ----------------
__global__ __launch_bounds__(256) void linear_k(const float* __restrict__ x,
                                                const float* __restrict__ W,
                                                const float* __restrict__ bias,
                                                const float* __restrict__ inv,
                                                __half* __restrict__ h, int N) {
    __shared__ float Ws[F_DIM][F_DIM];
    __shared__ float bs[F_DIM];
    for (int i = threadIdx.x; i < F_DIM * F_DIM; i += 256) Ws[i >> 6][i & 63] = W[i];
    if (threadIdx.x < F_DIM) bs[threadIdx.x] = bias[threadIdx.x];
    __syncthreads();

    int n = blockIdx.x * 256 + threadIdx.x;
    if (n >= N) return;

    float xr[F_DIM];
    const float4* xp = (const float4*)(x + (size_t)n * F_DIM);
#pragma unroll
    for (int k4 = 0; k4 < 16; ++k4) {
        float4 v = xp[k4];
        xr[k4 * 4 + 0] = v.x; xr[k4 * 4 + 1] = v.y;
        xr[k4 * 4 + 2] = v.z; xr[k4 * 4 + 3] = v.w;
    }
    float invn = inv[n];
    __half* hp = h + (size_t)n * F_DIM;
#pragma unroll 1
    for (int f0 = 0; f0 < F_DIM; f0 += 4) {
        float a0 = bs[f0 + 0], a1 = bs[f0 + 1], a2 = bs[f0 + 2], a3 = bs[f0 + 3];
#pragma unroll
        for (int k = 0; k < F_DIM; ++k) {
            float xv = xr[k];
            a0 += xv * Ws[k][f0 + 0];
            a1 += xv * Ws[k][f0 + 1];
            a2 += xv * Ws[k][f0 + 2];
            a3 += xv * Ws[k][f0 + 3];
        }
        union { __half2 h2[2]; float2 f2; } u;
        u.h2[0] = __floats2half2_rn(a0 * invn, a1 * invn);
        u.h2[1] = __floats2half2_rn(a2 * invn, a3 * invn);
        *((float2*)(hp + f0)) = u.f2;
    }
}

// ---------------- gelu (tanh approximation, jax.nn.gelu default) ----------------
__device__ __forceinline__ float gelu1(float x) {
    float x3 = x * x * x;
    float t = tanhf(0.7978845608028654f * (x + 0.044715f * x3));
    return 0.5f * x * (1.0f + t);
}

// ---------------- gather: wave per node; 4 edge-slots x 16 lanes; 8B loads; 16 edges in flight ----------------
__global__ __launch_bounds__(256) void gather_k(const __half* __restrict__ h,    // h_pre [N][64]
                                                const float* __restrict__ inv,
                                                const unsigned int* __restrict__ rowinfo,
                                                const unsigned int* __restrict__ esrc,
                                                float* __restrict__ out, int N) {
    int n = blockIdx.x * 4 + (threadIdx.x >> 6);
    if (n >= N) return;
    int lane = threadIdx.x & 63;
    int eslot = lane >> 4;      // 0..3: edge slot
    int fq = lane & 15;         // feature quad (halves 4fq..4fq+3)

    unsigned int ri = rowinfo[n];
    int beg = (int)(ri & 0x3FFFFFu);
    int deg = (int)(ri >> 22);

    float ax = 0.f, ay = 0.f, az = 0.f, aw = 0.f;
    int k = eslot;
    // unroll 4: 16 edges in flight per wave
    for (; k + 12 < deg; k += 16) {
        int s0 = (int)esrc[beg + k];
        int s1 = (int)esrc[beg + k + 4];
        int s2 = (int)esrc[beg + k + 8];
        int s3 = (int)esrc[beg + k + 12];
        float2 p0 = *((const float2*)(h + (size_t)s0 * F_DIM) + fq);
        float2 p1 = *((const float2*)(h + (size_t)s1 * F_DIM) + fq);
        float2 p2 = *((const float2*)(h + (size_t)s2 * F_DIM) + fq);
        float2 p3 = *((const float2*)(h + (size_t)s3 * F_DIM) + fq);
        union { float2 f; __half2 h2[2]; } u0, u1, u2, u3;
        u0.f = p0; u1.f = p1; u2.f = p2; u3.f = p3;
        float2 a, b;
        a = __half22float2(u0.h2[0]); b = __half22float2(u0.h2[1]);
        ax += a.x; ay += a.y; az += b.x; aw += b.y;
        a = __half22float2(u1.h2[0]); b = __half22float2(u1.h2[1]);
        ax += a.x; ay += a.y; az += b.x; aw += b.y;
        a = __half22float2(u2.h2[0]); b = __half22float2(u2.h2[1]);
        ax += a.x; ay += a.y; az += b.x; aw += b.y;
        a = __half22float2(u3.h2[0]); b = __half22float2(u3.h2[1]);
        ax += a.x; ay += a.y; az += b.x; aw += b.y;
    }
    for (; k < deg; k += 4) {
        int s0 = (int)esrc[beg + k];
        float2 p0 = *((const float2*)(h + (size_t)s0 * F_DIM) + fq);
        union { float2 f; __half2 h2[2]; } u0;
        u0.f = p0;
        float2 a = __half22float2(u0.h2[0]);
        float2 b = __half22float2(u0.h2[1]);
        ax += a.x; ay += a.y; az += b.x; aw += b.y;
    }
    // reduce across the 4 edge slots
    ax += __shfl_xor(ax, 16); ay += __shfl_xor(ay, 16);
    az += __shfl_xor(az, 16); aw += __shfl_xor(aw, 16);
    ax += __shfl_xor(ax, 32); ay += __shfl_xor(ay, 32);
    az += __shfl_xor(az, 32); aw += __shfl_xor(aw, 32);

    if (eslot == 0) {
        float invn = inv[n];
        union { float2 f; __half2 h2[2]; } us;
        us.f = *((const float2*)(h + (size_t)n * F_DIM) + fq);
        float2 s0 = __half22float2(us.h2[0]);
        float2 s1 = __half22float2(us.h2[1]);
        // self: h_pre[n] = h[n]*invn; final *invn gives h[n]*invn^2
        float4 o;
        o.x = gelu1((ax + s0.x) * invn);
        o.y = gelu1((ay + s0.y) * invn);
        o.z = gelu1((az + s1.x) * invn);
        o.w = gelu1((aw + s1.y) * invn);
        ((float4*)(out + (size_t)n * F_DIM))[fq] = o;
    }
}

extern "C" void kernel_launch(void* const* d_in, const int* in_sizes, int n_in,
                              void* d_out, int out_size, void* d_ws, size_t ws_size,
                              hipStream_t stream) {
    const float* x    = (const float*)d_in[0];
    const int*   ei   = (const int*)d_in[1];
    const float* W    = (const float*)d_in[2];
    const float* bias = (const float*)d_in[3];
    float* out = (float*)d_out;

    const int* src = ei;             // edge_index[0]
    const int* dst = ei + N_EDGES;   // edge_index[1]

    // workspace (~26.5 MB)
    unsigned int* tmp     = (unsigned int*)d_ws;              // NBUCK*CAP uints = 12.8 MB (doubles as esrc, in-place)
    unsigned int* rowinfo = tmp + (size_t)NBUCK * CAP;        // N uints
    float*        inv     = (float*)(rowinfo + N_NODES);      // N floats
    int*          bcur    = (int*)(inv + N_NODES);            // NBUCK ints
    size_t off = (size_t)(bcur + NBUCK) - (size_t)d_ws;
    off = (off + 31) & ~(size_t)31;
    __half* h = (__half*)((char*)d_ws + off);                 // N*64 halves = 12.8 MB

    init_k<<<(NBUCK + 255) / 256, 256, 0, stream>>>(bcur);
    pass1_k<<<(N_EDGES + TILE - 1) / TILE, 256, 0, stream>>>(src, dst, bcur, tmp, N_EDGES);
    passB_k<<<NBUCK, 256, 0, stream>>>(tmp, bcur, rowinfo, inv);
    linear_k<<<(N_NODES + 255) / 256, 256, 0, stream>>>(x, W, bias, inv, h, N_NODES);
    gather_k<<<(N_NODES + 3) / 4, 256, 0, stream>>>(h, inv, rowinfo, tmp, out, N_NODES);
}